// Round 2
// baseline (592.949 us; speedup 1.0000x reference)
//
#include <hip/hip_runtime.h>
#include <hip/hip_bf16.h>

#define B_   4
#define DENC 512
#define T_   200
#define DDEC 640
#define U_   100
#define H_   640
#define V_   1025
#define VPAD 1152   // 9 * 128

typedef float f32x4 __attribute__((ext_vector_type(4)));
typedef __bf16 bf16x8 __attribute__((ext_vector_type(8)));

__device__ __forceinline__ unsigned addrelu_pk(unsigned e, unsigned d) {
    // e,d: two packed bf16 each. returns packed bf16( relu(e+d) )
    float elo = __uint_as_float(e << 16);
    float ehi = __uint_as_float(e & 0xffff0000u);
    float dlo = __uint_as_float(d << 16);
    float dhi = __uint_as_float(d & 0xffff0000u);
    float lo = fmaxf(elo + dlo, 0.f);
    float hi = fmaxf(ehi + dhi, 0.f);
    unsigned r;
    asm("v_cvt_pk_bf16_f32 %0, %1, %2" : "=v"(r) : "v"(lo), "v"(hi));
    return r;
}

// ---------------- K1: enc_proj[b,t,h] = bf16( sum_d enc[b,d,t]*W_enc[d,h] + b_enc[h] )
__global__ __launch_bounds__(256) void enc_proj_kernel(
    const float* __restrict__ enc, const float* __restrict__ W,
    const float* __restrict__ bias, __hip_bfloat16* __restrict__ out)
{
    int hc = blockIdx.x, tt = blockIdx.y, b = blockIdx.z;
    int t0 = tt * 16, h0 = hc * 128;
    __shared__ float S[DENC][16];
    int tid = threadIdx.x;
    bool full = (t0 + 16 <= T_);
    for (int s = tid; s < DENC * 4; s += 256) {
        int d = s >> 2, j4 = (s & 3) * 4;
        const float* src = enc + ((size_t)b * DENC + d) * T_ + t0 + j4;
        if (full) {
            float4 v = *(const float4*)src;
            S[d][j4+0] = v.x; S[d][j4+1] = v.y; S[d][j4+2] = v.z; S[d][j4+3] = v.w;
        } else {
            #pragma unroll
            for (int c = 0; c < 4; ++c) {
                int t = t0 + j4 + c;
                S[d][j4+c] = (t < T_) ? src[c] : 0.f;
            }
        }
    }
    __syncthreads();
    int h = h0 + (tid & 127);
    int tg = tid >> 7;
    float acc[8] = {0.f,0.f,0.f,0.f,0.f,0.f,0.f,0.f};
    for (int d = 0; d < DENC; ++d) {
        float w = W[(size_t)d * H_ + h];
        const float* e = &S[d][tg * 8];
        #pragma unroll
        for (int i = 0; i < 8; ++i) acc[i] += w * e[i];
    }
    float bb = bias[h];
    #pragma unroll
    for (int i = 0; i < 8; ++i) {
        int t = t0 + tg * 8 + i;
        if (t < T_) out[((size_t)b * T_ + t) * H_ + h] = __float2bfloat16(acc[i] + bb);
    }
}

// ---------------- K2: dec_proj[b,u,h] = bf16( sum_d dec[b,d,u]*W_pred[d,h] + b_pred[h] )
__global__ __launch_bounds__(256) void dec_proj_kernel(
    const float* __restrict__ dec, const float* __restrict__ W,
    const float* __restrict__ bias, __hip_bfloat16* __restrict__ out)
{
    int hc = blockIdx.x, ut = blockIdx.y, b = blockIdx.z;
    int u0 = ut * 16, h0 = hc * 128;
    __shared__ float S[DDEC][16];
    int tid = threadIdx.x;
    bool full = (u0 + 16 <= U_);
    for (int s = tid; s < DDEC * 4; s += 256) {
        int d = s >> 2, j4 = (s & 3) * 4;
        const float* src = dec + ((size_t)b * DDEC + d) * U_ + u0 + j4;
        if (full) {
            float4 v = *(const float4*)src;
            S[d][j4+0] = v.x; S[d][j4+1] = v.y; S[d][j4+2] = v.z; S[d][j4+3] = v.w;
        } else {
            #pragma unroll
            for (int c = 0; c < 4; ++c) {
                int u = u0 + j4 + c;
                S[d][j4+c] = (u < U_) ? src[c] : 0.f;
            }
        }
    }
    __syncthreads();
    int h = h0 + (tid & 127);
    int ug = tid >> 7;
    float acc[8] = {0.f,0.f,0.f,0.f,0.f,0.f,0.f,0.f};
    for (int d = 0; d < DDEC; ++d) {
        float w = W[(size_t)d * H_ + h];
        const float* e = &S[d][ug * 8];
        #pragma unroll
        for (int i = 0; i < 8; ++i) acc[i] += w * e[i];
    }
    float bb = bias[h];
    #pragma unroll
    for (int i = 0; i < 8; ++i) {
        int u = u0 + ug * 8 + i;
        if (u < U_) out[((size_t)b * U_ + u) * H_ + h] = __float2bfloat16(acc[i] + bb);
    }
}

// ---------------- K3: Wt[v][h] = bf16(W_out[h][v]), v padded to VPAD with zeros
__global__ __launch_bounds__(256) void wt_transpose_kernel(
    const float* __restrict__ W, unsigned short* __restrict__ Wt)
{
    int hc = blockIdx.x, vc = blockIdx.y;
    int h0 = hc * 64, v0 = vc * 64;
    __shared__ float tile[64][65];
    int tid = threadIdx.x;
    #pragma unroll
    for (int it = 0; it < 16; ++it) {
        int hl = it * 4 + (tid >> 6);
        int vl = tid & 63;
        int v = v0 + vl;
        tile[hl][vl] = (v < V_) ? W[(size_t)(h0 + hl) * V_ + v] : 0.f;
    }
    __syncthreads();
    #pragma unroll
    for (int it = 0; it < 16; ++it) {
        int vl = it * 4 + (tid >> 6);
        int hl = tid & 63;
        __bf16 bv = (__bf16)tile[hl][vl];
        Wt[(size_t)(v0 + vl) * H_ + h0 + hl] = *(unsigned short*)&bv;
    }
}

// ---------------- K4: fused joint kernel with cooperative LDS X-build
// block: 256 thr = 4 waves (2x2), tile 128 rows (16t x 8u) x 128 v-cols, wave 64x64
// K-loop: 10 steps of K=64, X double-buffered in LDS, 1 barrier/step
__global__ __launch_bounds__(256) void joint_kernel(
    const __hip_bfloat16* __restrict__ encP,   // [B,T,H] bf16
    const __hip_bfloat16* __restrict__ decP,   // [B,U,H] bf16
    const unsigned short* __restrict__ Wt,     // [VPAD][H] bf16
    const float* __restrict__ b_out,           // [V]
    float* __restrict__ out)                   // [B,T,U,V] f32
{
    // X tile: [128 rows][64 k] bf16, stored as 16B chunks with XOR swizzle:
    // physical chunk = logical_chunk ^ (row & 7)  (row stride 128 B)
    __shared__ uint4 Xs[2][128][8];            // 32 KB

    int nt = blockIdx.x;                       // v tile 0..8
    int tu = blockIdx.y;                       // 0..168
    int b  = blockIdx.z;
    int tt = tu / 13, ut = tu % 13;
    int t0 = tt * 16, u0 = ut * 8, vb = nt * 128;
    int tid = threadIdx.x;
    int lane = tid & 63, wid = tid >> 6;
    int wr = wid >> 1, wc = wid & 1;
    int lrow = lane & 15, kg = lane >> 4;

    // ---- X-build mapping: thread owns row r, chunk set {half, half+2, half+4, half+6}
    int r    = tid & 127;
    int half = tid >> 7;
    int tb = t0 + (r >> 3); if (tb > T_ - 1) tb = T_ - 1;
    int ub = u0 + (r & 7);  if (ub > U_ - 1) ub = U_ - 1;
    const unsigned short* eRow = (const unsigned short*)encP + ((size_t)b * T_ + tb) * H_;
    const unsigned short* dRow = (const unsigned short*)decP + ((size_t)b * U_ + ub) * H_;

    // ---- B pointers (global, L2-resident)
    const unsigned short* wp[4];
    #pragma unroll
    for (int j = 0; j < 4; ++j) {
        int v = vb + wc * 64 + j * 16 + lrow;
        wp[j] = Wt + (size_t)v * H_ + kg * 8;
    }

    f32x4 acc[4][4];
    #pragma unroll
    for (int i = 0; i < 4; ++i)
        #pragma unroll
        for (int j = 0; j < 4; ++j)
            acc[i][j] = (f32x4){0.f, 0.f, 0.f, 0.f};

    uint4 E[4], D[4];

    // ---- prologue: load + build X for k-step 0 into buf 0
    #pragma unroll
    for (int p = 0; p < 4; ++p) {
        int k8 = half + 2 * p;
        E[p] = *(const uint4*)(eRow + k8 * 8);
        D[p] = *(const uint4*)(dRow + k8 * 8);
    }
    #pragma unroll
    for (int p = 0; p < 4; ++p) {
        int k8 = half + 2 * p;
        uint4 x;
        x.x = addrelu_pk(E[p].x, D[p].x);
        x.y = addrelu_pk(E[p].y, D[p].y);
        x.z = addrelu_pk(E[p].z, D[p].z);
        x.w = addrelu_pk(E[p].w, D[p].w);
        Xs[0][r][k8 ^ (r & 7)] = x;
    }
    __syncthreads();

    // ---- main K loop
    #pragma unroll 1
    for (int t = 0; t < 10; ++t) {
        int cur = t & 1;
        // issue next-step global loads early (hide L2 latency under MFMA)
        if (t < 9) {
            int kb = (t + 1) * 64;
            #pragma unroll
            for (int p = 0; p < 4; ++p) {
                int k8 = half + 2 * p;
                E[p] = *(const uint4*)(eRow + kb + k8 * 8);
                D[p] = *(const uint4*)(dRow + kb + k8 * 8);
            }
        }
        // consume current buffer
        #pragma unroll
        for (int h = 0; h < 2; ++h) {
            bf16x8 av[4], bv[4];
            #pragma unroll
            for (int i = 0; i < 4; ++i) {
                int row = wr * 64 + i * 16 + lrow;
                uint4 raw = Xs[cur][row][(h * 4 + kg) ^ (row & 7)];
                av[i] = __builtin_bit_cast(bf16x8, raw);
            }
            #pragma unroll
            for (int j = 0; j < 4; ++j)
                bv[j] = *(const bf16x8*)(wp[j] + t * 64 + h * 32);
            #pragma unroll
            for (int i = 0; i < 4; ++i)
                #pragma unroll
                for (int j = 0; j < 4; ++j)
                    acc[i][j] = __builtin_amdgcn_mfma_f32_16x16x32_bf16(av[i], bv[j], acc[i][j], 0, 0, 0);
        }
        // build next buffer
        if (t < 9) {
            #pragma unroll
            for (int p = 0; p < 4; ++p) {
                int k8 = half + 2 * p;
                uint4 x;
                x.x = addrelu_pk(E[p].x, D[p].x);
                x.y = addrelu_pk(E[p].y, D[p].y);
                x.z = addrelu_pk(E[p].z, D[p].z);
                x.w = addrelu_pk(E[p].w, D[p].w);
                Xs[cur ^ 1][r][k8 ^ (r & 7)] = x;
            }
        }
        __syncthreads();
    }

    // ---- epilogue: D layout col = lane&15, row = (lane>>4)*4 + q
    #pragma unroll
    for (int j = 0; j < 4; ++j) {
        int v = vb + wc * 64 + j * 16 + lrow;
        float bo = (v < V_) ? b_out[v] : 0.f;
        #pragma unroll
        for (int i = 0; i < 4; ++i) {
            #pragma unroll
            for (int q = 0; q < 4; ++q) {
                int row = wr * 64 + i * 16 + kg * 4 + q;
                int t = t0 + (row >> 3);
                int u = u0 + (row & 7);
                if (t < T_ && u < U_ && v < V_)
                    out[(((size_t)b * T_ + t) * U_ + u) * V_ + v] = acc[i][j][q] + bo;
            }
        }
    }
}

extern "C" void kernel_launch(void* const* d_in, const int* in_sizes, int n_in,
                              void* d_out, int out_size, void* d_ws, size_t ws_size,
                              hipStream_t stream) {
    const float* enc    = (const float*)d_in[0];   // [4,512,200]
    const float* dec    = (const float*)d_in[1];   // [4,640,100]
    const float* W_enc  = (const float*)d_in[2];   // [512,640]
    const float* b_enc  = (const float*)d_in[3];   // [640]
    const float* W_pred = (const float*)d_in[4];   // [640,640]
    const float* b_pred = (const float*)d_in[5];   // [640]
    const float* W_out  = (const float*)d_in[6];   // [640,1025]
    const float* b_out  = (const float*)d_in[7];   // [1025]
    float* out = (float*)d_out;

    char* ws = (char*)d_ws;
    __hip_bfloat16* encP = (__hip_bfloat16*)ws;                       // 4*200*640*2 = 1,024,000
    __hip_bfloat16* decP = (__hip_bfloat16*)(ws + 1024000);           // 4*100*640*2 =   512,000
    unsigned short* Wt   = (unsigned short*)(ws + 1024000 + 512000);  // 1152*640*2  = 1,474,560

    enc_proj_kernel<<<dim3(5, 13, 4), 256, 0, stream>>>(enc, W_enc, b_enc, encP);
    dec_proj_kernel<<<dim3(5, 7, 4), 256, 0, stream>>>(dec, W_pred, b_pred, decP);
    wt_transpose_kernel<<<dim3(10, 18), 256, 0, stream>>>(W_out, Wt);
    joint_kernel<<<dim3(9, 169, 4), 256, 0, stream>>>(encP, decP, Wt, b_out, out);
}